// Round 5
// baseline (324.297 us; speedup 1.0000x reference)
//
#include <hip/hip_runtime.h>
#include <hip/hip_bf16.h>
#include <float.h>

#define B 4
#define L 1024
#define H 768
#define HEADS 12
#define E 22
#define MPD 128
#define EMB 512
#define M (B*MPD)      // 512 mentions
#define NE (B*E)       // 88 entities
#define LCH_A 4        // l-chunks per entity in k_gather (256 l each)
#define LCH_B 16       // l-chunks in k_context
#define LB (L/LCH_B)   // 64

// ---------------------------------------------------------------------------
// K1: fused gather stage, 256 threads/block.
//   blocks [0, NE*LCH_A): raw attention segment-sum for (entity e, l-chunk)
//       e_att_raw[e, l] = sum_{m in e} sum_hd att[b(m), hd, pos(m), l]
//       zpart[block]    = partial row-sum (for the norm scalar)
//       cntf[e]         = mention count (chunk 0 writes)
//   blocks [NE*LCH_A, ...+NE): per-entity logsumexp of gathered seq rows
//       -> entity_emb (its own buffer; no ordering vs K2 needed)
// ---------------------------------------------------------------------------
__global__ __launch_bounds__(256) void k_gather(
    const float* __restrict__ seq, const float* __restrict__ att,
    const int* __restrict__ m_batch, const int* __restrict__ m_pos,
    const int* __restrict__ m_ent,
    float* __restrict__ e_att_raw, float* __restrict__ entity_emb,
    float* __restrict__ zpart, float* __restrict__ cntf)
{
    const int bx = blockIdx.x;
    const int t  = threadIdx.x;
    __shared__ int s_cnt;
    __shared__ size_t s_off[MPD];
    __shared__ float s_p[4];
    if (t == 0) s_cnt = 0;
    __syncthreads();

    if (bx < NE * LCH_A) {
        const int e = bx >> 2, chunk = bx & 3;
        for (int m = t; m < M; m += 256)
            if (m_ent[m] == e) {
                int p = atomicAdd(&s_cnt, 1);
                s_off[p] = (size_t)m_batch[m] * HEADS * L * L + (size_t)m_pos[m] * L;
            }
        __syncthreads();
        const int cnt = s_cnt;
        const int l = chunk * 256 + t;
        float acc = 0.f;
        for (int i = 0; i < cnt; ++i) {
            const float* p = att + s_off[i] + l;
            #pragma unroll
            for (int hd = 0; hd < HEADS; ++hd)
                acc += p[(size_t)hd * L * L];
        }
        e_att_raw[(size_t)e * L + l] = acc;
        float v = acc;
        #pragma unroll
        for (int off = 32; off > 0; off >>= 1) v += __shfl_xor(v, off, 64);
        if ((t & 63) == 0) s_p[t >> 6] = v;
        __syncthreads();
        if (t == 0) {
            zpart[bx] = s_p[0] + s_p[1] + s_p[2] + s_p[3];
            if (chunk == 0) cntf[e] = (float)cnt;
        }
    } else {
        const int e = bx - NE * LCH_A;
        for (int m = t; m < M; m += 256)
            if (m_ent[m] == e) {
                int p = atomicAdd(&s_cnt, 1);
                s_off[p] = ((size_t)m_batch[m] * L + m_pos[m]) * H;
            }
        __syncthreads();
        const int cnt = s_cnt;
        float mx0 = -FLT_MAX, mx1 = -FLT_MAX, mx2 = -FLT_MAX;
        for (int i = 0; i < cnt; ++i) {
            const float* r = seq + s_off[i];
            mx0 = fmaxf(mx0, r[t]);
            mx1 = fmaxf(mx1, r[t + 256]);
            mx2 = fmaxf(mx2, r[t + 512]);
        }
        float s0 = 0.f, s1 = 0.f, s2 = 0.f;
        for (int i = 0; i < cnt; ++i) {
            const float* r = seq + s_off[i];
            s0 += expf(r[t]       - mx0);
            s1 += expf(r[t + 256] - mx1);
            s2 += expf(r[t + 512] - mx2);
        }
        float o0, o1, o2;
        if (cnt > 0) {
            o0 = logf(s0 + 1e-30f) + mx0;
            o1 = logf(s1 + 1e-30f) + mx1;
            o2 = logf(s2 + 1e-30f) + mx2;
        } else { o0 = o1 = o2 = 0.f; }
        float* dst = entity_emb + (size_t)e * H;
        dst[t] = o0; dst[t + 256] = o1; dst[t + 512] = o2;
    }
}

// ---------------------------------------------------------------------------
// K2: raw context partials, NO atomics, NO norm.
//   grid (H/256, LCH_B, B), block 128, float2 per thread (h, h+1).
//   ctx_part[lc][b*E+e][h] = sum_{dl<LB} e_att_raw[e][l0+dl] * seq[b,l0+dl,h]
// ---------------------------------------------------------------------------
__global__ __launch_bounds__(128) void k_context(
    const float* __restrict__ seq, const float* __restrict__ e_att_raw,
    float* __restrict__ ctx_part)
{
    const int ht = blockIdx.x;   // 0..2
    const int lc = blockIdx.y;   // 0..LCH_B-1
    const int b  = blockIdx.z;
    const int t  = threadIdx.x;
    const int h  = ht * 256 + t * 2;
    const int l0 = lc * LB;
    __shared__ float s_att[E][LB];
    for (int i = t; i < E * LB; i += 128) {
        int el = i / LB, dl = i % LB;
        s_att[el][dl] = e_att_raw[(size_t)(b * E + el) * L + l0 + dl];
    }
    __syncthreads();
    float ax[E], ay[E];
    #pragma unroll
    for (int e = 0; e < E; ++e) { ax[e] = 0.f; ay[e] = 0.f; }
    const float* sp = seq + ((size_t)b * L + l0) * H + h;
    #pragma unroll 4
    for (int dl = 0; dl < LB; ++dl) {
        const float2 s = *(const float2*)(sp + (size_t)dl * H);
        #pragma unroll
        for (int e = 0; e < E; ++e) {
            ax[e] += s_att[e][dl] * s.x;
            ay[e] += s_att[e][dl] * s.y;
        }
    }
    #pragma unroll
    for (int e = 0; e < E; ++e) {
        float2 v; v.x = ax[e]; v.y = ay[e];
        *(float2*)&ctx_part[((size_t)lc * NE + b * E + e) * H + h] = v;
    }
}

// ---------------------------------------------------------------------------
// K3: finalize + output GEMM.
//   grid (NE, EMB/128), block 128. Prologue: s_row[h] =
//   (sum_lc ctx_part[lc][row][h]) * norm[row] + entity_emb[row][h],
//   norm = 1/(Zraw + 1e-5*(cnt+1e-5)*HEADS) — exactly the reference chain.
//   Then out[row,c] = tanh(dot(s_row, w[:,c]) + bias[c]).
// ---------------------------------------------------------------------------
__global__ __launch_bounds__(128) void k_out(
    const float* __restrict__ ctx_part, const float* __restrict__ entity_emb,
    const float* __restrict__ zpart, const float* __restrict__ cntf,
    const float* __restrict__ w, const float* __restrict__ bias,
    float* __restrict__ out)
{
    const int row = blockIdx.x;
    const int c   = blockIdx.y * 128 + threadIdx.x;
    __shared__ float s_row[H];
    const float z = zpart[row * LCH_A] + zpart[row * LCH_A + 1]
                  + zpart[row * LCH_A + 2] + zpart[row * LCH_A + 3];
    const float norm = 1.f / (z + 1e-5f * ((cntf[row] + 1e-5f) * (float)HEADS));
    for (int h = threadIdx.x; h < H; h += 128) {
        float sum = 0.f;
        #pragma unroll
        for (int lc = 0; lc < LCH_B; ++lc)
            sum += ctx_part[((size_t)lc * NE + row) * H + h];
        s_row[h] = sum * norm + entity_emb[(size_t)row * H + h];
    }
    __syncthreads();
    float acc = bias[c];
    #pragma unroll 8
    for (int h = 0; h < H; ++h)
        acc += s_row[h] * w[(size_t)h * EMB + c];
    out[(size_t)row * EMB + c] = tanhf(acc);
}

extern "C" void kernel_launch(void* const* d_in, const int* in_sizes, int n_in,
                              void* d_out, int out_size, void* d_ws, size_t ws_size,
                              hipStream_t stream) {
    const float* seq   = (const float*)d_in[0];
    const float* att   = (const float*)d_in[1];
    const float* w     = (const float*)d_in[2];
    const float* bias  = (const float*)d_in[3];
    const int* m_batch = (const int*)d_in[4];
    const int* m_pos   = (const int*)d_in[5];
    const int* m_ent   = (const int*)d_in[6];
    float* out = (float*)d_out;

    float* ws         = (float*)d_ws;
    float* e_att_raw  = ws;                                  // NE*L       = 90112
    float* entity_emb = e_att_raw + (size_t)NE * L;          // NE*H       = 67584
    float* zpart      = entity_emb + (size_t)NE * H;         // NE*LCH_A   = 352
    float* cntf       = zpart + NE * LCH_A;                  // NE         = 88
    float* ctx_part   = cntf + NE;                           // LCH_B*NE*H = 1081344

    k_gather<<<NE * LCH_A + NE, 256, 0, stream>>>(
        seq, att, m_batch, m_pos, m_ent, e_att_raw, entity_emb, zpart, cntf);
    dim3 gB(H / 256, LCH_B, B);
    k_context<<<gB, 128, 0, stream>>>(seq, e_att_raw, ctx_part);
    dim3 gC(NE, EMB / 128);
    k_out<<<gC, 128, 0, stream>>>(ctx_part, entity_emb, zpart, cntf, w, bias, out);
}